// Round 15
// baseline (562.529 us; speedup 1.0000x reference)
//
#include <hip/hip_runtime.h>
#include <hip/hip_bf16.h>
#include <hip/hip_cooperative_groups.h>
#include <math.h>

namespace cg = cooperative_groups;

#define BB 4
#define LL 2048
#define DM 128
#define DI 256
#define DS 16
#define DTR 8
#define NB 6
#define KPRE 7
#define KC 8
#define NC 128      // chunks per sequence
#define CT 16       // chunk length (NC*CT == LL)
#define NCHUNK (BB*NC)   // 512 == cooperative grid
#define BL (BB*LL)  // 8192 tokens
#define SU 4        // scan unroll factor (fallback scans)

typedef __attribute__((ext_vector_type(8))) short short8v;
typedef __attribute__((ext_vector_type(4))) short short4v;
typedef __attribute__((ext_vector_type(4))) float f32x4;

// ---- bf16 pack/unpack helpers ----
__device__ __forceinline__ void store_bf16x4(__hip_bfloat16* p, float a, float b, float c, float d) {
    __hip_bfloat16 t[4] = {__float2bfloat16(a), __float2bfloat16(b),
                           __float2bfloat16(c), __float2bfloat16(d)};
    *(short4v*)p = *(const short4v*)t;
}
__device__ __forceinline__ float4 load_bf16x4(const __hip_bfloat16* p) {
    short4v raw = *(const short4v*)p;
    const __hip_bfloat16* t = (const __hip_bfloat16*)&raw;
    return make_float4(__bfloat162float(t[0]), __bfloat162float(t[1]),
                       __bfloat162float(t[2]), __bfloat162float(t[3]));
}
__device__ __forceinline__ void load_bf16x16(const __hip_bfloat16* p, float* o) {
    short8v a = *(const short8v*)p;
    short8v b = *(const short8v*)(p + 8);
    const __hip_bfloat16* ta = (const __hip_bfloat16*)&a;
    const __hip_bfloat16* tb = (const __hip_bfloat16*)&b;
#pragma unroll
    for (int i = 0; i < 8; ++i) { o[i] = __bfloat162float(ta[i]); o[8 + i] = __bfloat162float(tb[i]); }
}
__device__ __forceinline__ void store_bf16x16(__hip_bfloat16* p, const float* v) {
    __hip_bfloat16 t[16];
#pragma unroll
    for (int i = 0; i < 16; ++i) t[i] = __float2bfloat16(v[i]);
    *(short8v*)p = *(const short8v*)t;
    *(short8v*)(p + 8) = *(const short8v*)(t + 8);
}

// ================= shared phase bodies =================

__device__ __forceinline__ void dev_preconv(int idx,
    const float* __restrict__ x, const float* __restrict__ w, const float* __restrict__ bias,
    float* __restrict__ h, const float* __restrict__ Wi, const float* __restrict__ Wo,
    __hip_bfloat16* __restrict__ wi, __hip_bfloat16* __restrict__ wo) {
    int d = idx & (DM - 1);
    int l = (idx >> 7) & (LL - 1);
    int b = idx >> 18;
    float acc = bias[d];
#pragma unroll
    for (int k = 0; k < KPRE; ++k) {
        int pos = l + k - 3;
        float xv = (pos >= 0 && pos < LL) ? x[b * LL + pos] : 0.f;
        acc = fmaf(xv, w[d * KPRE + k], acc);
    }
    h[idx] = 0.5f * acc * (1.f + erff(acc * 0.70710678118654752f));
    if (idx < NB * 2 * DI * DM) wi[idx] = __float2bfloat16(Wi[idx]);
    if (idx < NB * DM * DI)     wo[idx] = __float2bfloat16(Wo[idx]);
}

// ---- mega phase A: LN + GEMM1 (xi,z in LDS) + conv + Wx + delta + scan1 + decoupled lookback ----
__device__ __forceinline__ void dev_phaseA(int chunk, int tid, int epoch,
    const float* __restrict__ h, const float* __restrict__ lw, const float* __restrict__ lb,
    const __hip_bfloat16* __restrict__ Wi,
    const float* __restrict__ cw, const float* __restrict__ cbs,
    const float* __restrict__ Wx, const float* __restrict__ Wdt, const float* __restrict__ bdt,
    const float* __restrict__ A_log,
    __hip_bfloat16* __restrict__ Pst, __hip_bfloat16* __restrict__ hend,
    __hip_bfloat16* __restrict__ hincl, int* __restrict__ flags,
    __hip_bfloat16* As, __hip_bfloat16 (*xi_s)[DI],
    float (*xc_s)[DI], float (*dl_s)[DI], float (*bc_s)[32],
    __hip_bfloat16 (*z_s)[DI], __hip_bfloat16 (*hin_s)[DS]) {
    int c = chunk & (NC - 1);
    int b = chunk >> 7;                 // NC=128
    int wave = tid >> 6, lane = tid & 63;
    // ---- LN: 32 rows = 16 halo/pad + 16 chunk tokens; rows with tl<0 -> zeros ----
    for (int it = 0; it < 8; ++it) {
        int lr = wave * 8 + it;
        int tl = c * CT + lr - 16;
        int sw = (lr & 7) << 3;
        if (tl >= 0) {
            int t = b * LL + tl;
            float v0 = h[t * DM + lane];
            float v1 = h[t * DM + lane + 64];
            float s = v0 + v1;
#pragma unroll
            for (int off = 32; off; off >>= 1) s += __shfl_xor(s, off);
            float mean = s * (1.f / 128.f);
            float d0 = v0 - mean, d1 = v1 - mean;
            float q = d0 * d0 + d1 * d1;
#pragma unroll
            for (int off = 32; off; off >>= 1) q += __shfl_xor(q, off);
            float rstd = rsqrtf(q * (1.f / 128.f) + 1e-5f);
            As[lr * 128 + (lane ^ sw)]        = __float2bfloat16(d0 * rstd * lw[lane] + lb[lane]);
            As[lr * 128 + ((lane + 64) ^ sw)] = __float2bfloat16(d1 * rstd * lw[lane + 64] + lb[lane + 64]);
        } else {
            As[lr * 128 + (lane ^ sw)]        = __float2bfloat16(0.f);
            As[lr * 128 + ((lane + 64) ^ sw)] = __float2bfloat16(0.f);
        }
    }
    __syncthreads();
    // ---- GEMM1: waves 0,1 -> xi (LDS); waves 2,3 -> z (LDS) ----
    {
        int r = lane & 15, kh = lane >> 4;
        short8v af[2][4];
#pragma unroll
        for (int mf = 0; mf < 2; ++mf)
#pragma unroll
            for (int k = 0; k < 4; ++k) {
                int row = mf * 16 + r;
                int cbk = k * 4 + kh;
                af[mf][k] = *(const short8v*)&As[row * 128 + ((cbk ^ (row & 7)) << 3)];
            }
        int nBase = wave * 128;
        for (int nf = 0; nf < 8; ++nf) {
            short8v bfr[4];
#pragma unroll
            for (int k = 0; k < 4; ++k)
                bfr[k] = *(const short8v*)&Wi[(size_t)(nBase + nf * 16 + r) * DM + k * 32 + kh * 8];
            if (wave < 2) {
                f32x4 acc0 = {}, acc1 = {};
#pragma unroll
                for (int k = 0; k < 4; ++k) {
                    acc0 = __builtin_amdgcn_mfma_f32_16x16x32_bf16(af[0][k], bfr[k], acc0, 0, 0, 0);
                    acc1 = __builtin_amdgcn_mfma_f32_16x16x32_bf16(af[1][k], bfr[k], acc1, 0, 0, 0);
                }
#pragma unroll
                for (int rg = 0; rg < 4; ++rg) {
                    xi_s[kh * 4 + rg][nBase + nf * 16 + r]      = __float2bfloat16(acc0[rg]);
                    xi_s[16 + kh * 4 + rg][nBase + nf * 16 + r] = __float2bfloat16(acc1[rg]);
                }
            } else {
                f32x4 acc1 = {};
#pragma unroll
                for (int k = 0; k < 4; ++k)
                    acc1 = __builtin_amdgcn_mfma_f32_16x16x32_bf16(af[1][k], bfr[k], acc1, 0, 0, 0);
#pragma unroll
                for (int rg = 0; rg < 4; ++rg)
                    z_s[kh * 4 + rg][(nBase - 256) + nf * 16 + r] = __float2bfloat16(acc1[rg]);
            }
        }
    }
    __syncthreads();
    // ---- conv + SiLU + Wx + delta (xi from LDS) ----
    for (int i = 0; i < 4; ++i) {
        int lt = wave * 4 + i;
        float xv[4];
        for (int j = 0; j < 4; ++j) {
            int e = lane + 64 * j;
            float4 c0 = *(const float4*)&cw[e * KC];
            float4 c1 = *(const float4*)&cw[e * KC + 4];
            float wts[8] = {c0.x, c0.y, c0.z, c0.w, c1.x, c1.y, c1.z, c1.w};
            float acc = cbs[e];
#pragma unroll
            for (int k = 0; k < KC; ++k)
                acc = fmaf(__bfloat162float(xi_s[lt + 9 + k][e]), wts[k], acc);
            xv[j] = acc / (1.f + __expf(-acc));
            xc_s[lt][e] = xv[j];
        }
        float dt8[8];
        float bcv = 0.f;
#pragma unroll
        for (int o = 0; o < 40; ++o) {
            const float* w = &Wx[o * DI];
            float s = xv[0] * w[lane];
            s = fmaf(xv[1], w[lane + 64], s);
            s = fmaf(xv[2], w[lane + 128], s);
            s = fmaf(xv[3], w[lane + 192], s);
#pragma unroll
            for (int off = 32; off; off >>= 1) s += __shfl_xor(s, off);
            if (o < 8) dt8[o] = s;
            else if (lane == o - 8) bcv = s;
        }
        if (lane < 32) bc_s[lt][lane] = bcv;
        for (int j = 0; j < 4; ++j) {
            int e = lane + 64 * j;
            float s = bdt[e];
#pragma unroll
            for (int r = 0; r < 8; ++r) s = fmaf(dt8[r], Wdt[e * 8 + r], s);
            dl_s[lt][e] = fmaxf(s, 0.f) + log1pf(__expf(-fabsf(s)));
        }
    }
    __syncthreads();
    // ---- chunk-local scan1: thread = channel e ----
    int e = tid;
    {
        float d16[CT], u16[CT];
#pragma unroll
        for (int l = 0; l < CT; ++l) { d16[l] = dl_s[l][e]; u16[l] = xc_s[l][e]; }
        for (int ng = 0; ng < 4; ++ng) {
            float4 al = *(const float4*)&A_log[e * DS + 4 * ng];
            float Aen[4] = {-__expf(al.x), -__expf(al.y), -__expf(al.z), -__expf(al.w)};
            float hh[4] = {}, Pl[4] = {1.f, 1.f, 1.f, 1.f};
#pragma unroll
            for (int l = 0; l < CT; ++l) {
                float du = d16[l] * u16[l];
                float4 bm = *(const float4*)&bc_s[l][4 * ng];
                float a0 = __expf(d16[l] * Aen[0]);
                float a1 = __expf(d16[l] * Aen[1]);
                float a2 = __expf(d16[l] * Aen[2]);
                float a3 = __expf(d16[l] * Aen[3]);
                hh[0] = fmaf(hh[0], a0, du * bm.x);
                hh[1] = fmaf(hh[1], a1, du * bm.y);
                hh[2] = fmaf(hh[2], a2, du * bm.z);
                hh[3] = fmaf(hh[3], a3, du * bm.w);
                Pl[0] *= a0; Pl[1] *= a1; Pl[2] *= a2; Pl[3] *= a3;
            }
            size_t oidx = (((size_t)(b * NC + c)) * DI + e) * DS + 4 * ng;
            store_bf16x4(&Pst[oidx], Pl[0], Pl[1], Pl[2], Pl[3]);
            store_bf16x4(&hend[oidx], hh[0], hh[1], hh[2], hh[3]);
        }
    }
    // ---- publish local state ----
    __threadfence();
    __syncthreads();
    if (tid == 0)
        __hip_atomic_store(&flags[b * NC + c], 2 * epoch,
                           __ATOMIC_RELEASE, __HIP_MEMORY_SCOPE_AGENT);
    // ---- decoupled lookback (batch 2, inclusive short-circuit) ----
    float hacc[16], Pacc[16];
#pragma unroll
    for (int n = 0; n < 16; ++n) { hacc[n] = 0.f; Pacc[n] = 1.f; }
    int j = c - 1;
    while (j >= 0) {
        int j2 = (j >= 1) ? j - 1 : j;
        int f1, f0;
        do {
            f1 = __hip_atomic_load(&flags[b * NC + j],  __ATOMIC_ACQUIRE, __HIP_MEMORY_SCOPE_AGENT);
            f0 = __hip_atomic_load(&flags[b * NC + j2], __ATOMIC_ACQUIRE, __HIP_MEMORY_SCOPE_AGENT);
            if (f1 < 2 * epoch || f0 < 2 * epoch) __builtin_amdgcn_s_sleep(2);
        } while (f1 < 2 * epoch || f0 < 2 * epoch);
        size_t bj = (((size_t)(b * NC + j)) * DI + e) * DS;
        if (f1 > 2 * epoch) {            // j holds inclusive prefix
            float hi[16]; load_bf16x16(&hincl[bj], hi);
#pragma unroll
            for (int n = 0; n < 16; ++n) hacc[n] = fmaf(Pacc[n], hi[n], hacc[n]);
            break;
        }
        float pj[16], he[16];
        load_bf16x16(&Pst[bj], pj);
        load_bf16x16(&hend[bj], he);
#pragma unroll
        for (int n = 0; n < 16; ++n) { hacc[n] = fmaf(Pacc[n], he[n], hacc[n]); Pacc[n] *= pj[n]; }
        if (j == 0) break;
        size_t bj0 = (((size_t)(b * NC + j - 1)) * DI + e) * DS;
        if (f0 > 2 * epoch) {            // j-1 holds inclusive prefix
            float hi[16]; load_bf16x16(&hincl[bj0], hi);
#pragma unroll
            for (int n = 0; n < 16; ++n) hacc[n] = fmaf(Pacc[n], hi[n], hacc[n]);
            break;
        }
        float pj0[16], he0[16];
        load_bf16x16(&Pst[bj0], pj0);
        load_bf16x16(&hend[bj0], he0);
#pragma unroll
        for (int n = 0; n < 16; ++n) { hacc[n] = fmaf(Pacc[n], he0[n], hacc[n]); Pacc[n] *= pj0[n]; }
        j -= 2;
    }
    // ---- own inclusive publish + hin to LDS ----
    {
        size_t bcx = (((size_t)(b * NC + c)) * DI + e) * DS;
        float pc[16], hc[16];
        load_bf16x16(&Pst[bcx], pc);
        load_bf16x16(&hend[bcx], hc);
#pragma unroll
        for (int n = 0; n < 16; ++n) {
            hin_s[e][n] = __float2bfloat16(hacc[n]);
            hc[n] = fmaf(pc[n], hacc[n], hc[n]);
        }
        store_bf16x16(&hincl[bcx], hc);
    }
    __threadfence();
    __syncthreads();
    if (tid == 0)
        __hip_atomic_store(&flags[b * NC + c], 2 * epoch + 1,
                           __ATOMIC_RELEASE, __HIP_MEMORY_SCOPE_AGENT);
}

// ---- mega phase B: chunk-local scan3 (hin from LDS) + gate (z from LDS) -> y LDS -> gemm2 ----
__device__ __forceinline__ void dev_fusedB(int chunk, int tid,
    const float* __restrict__ A_log, const float* __restrict__ Dsk,
    const __hip_bfloat16* __restrict__ Wo, float* __restrict__ hout,
    const float (*xc_s)[DI], const float (*dl_s)[DI], const float (*bc_s)[32],
    const __hip_bfloat16 (*z_s)[DI], const __hip_bfloat16 (*hin_s)[DS],
    __hip_bfloat16 (*y_s)[DI + 8]) {
    int c = chunk & (NC - 1);
    int b = chunk >> 7;
    int base = b * LL + c * CT;
    int e = tid;
    float d16[CT], u16[CT], yacc[CT];
    float dsk = Dsk[e];
#pragma unroll
    for (int l = 0; l < CT; ++l) {
        d16[l] = dl_s[l][e];
        u16[l] = xc_s[l][e];
        yacc[l] = dsk * u16[l];
    }
    for (int ng = 0; ng < 4; ++ng) {
        float4 al = *(const float4*)&A_log[e * DS + 4 * ng];
        float Aen[4] = {-__expf(al.x), -__expf(al.y), -__expf(al.z), -__expf(al.w)};
        float hh[4] = {__bfloat162float(hin_s[e][4 * ng]),
                       __bfloat162float(hin_s[e][4 * ng + 1]),
                       __bfloat162float(hin_s[e][4 * ng + 2]),
                       __bfloat162float(hin_s[e][4 * ng + 3])};
#pragma unroll
        for (int l = 0; l < CT; ++l) {
            float du = d16[l] * u16[l];
            float4 bm = *(const float4*)&bc_s[l][4 * ng];
            float4 cm = *(const float4*)&bc_s[l][16 + 4 * ng];
            float a0 = __expf(d16[l] * Aen[0]);
            float a1 = __expf(d16[l] * Aen[1]);
            float a2 = __expf(d16[l] * Aen[2]);
            float a3 = __expf(d16[l] * Aen[3]);
            hh[0] = fmaf(hh[0], a0, du * bm.x);
            hh[1] = fmaf(hh[1], a1, du * bm.y);
            hh[2] = fmaf(hh[2], a2, du * bm.z);
            hh[3] = fmaf(hh[3], a3, du * bm.w);
            float p = hh[0] * cm.x;
            p = fmaf(hh[1], cm.y, p);
            p = fmaf(hh[2], cm.z, p);
            p = fmaf(hh[3], cm.w, p);
            yacc[l] += p;
        }
    }
#pragma unroll
    for (int l = 0; l < CT; ++l) {
        float z = __bfloat162float(z_s[l][e]);
        y_s[l][e] = __float2bfloat16(yacc[l] * (z / (1.f + __expf(-z))));
    }
    __syncthreads();
    // gemm2: 16 rows x 128 cols, K=256; wave covers 32 cols
    int wave = tid >> 6, lane = tid & 63;
    int r  = lane & 15;
    int kh = lane >> 4;
    f32x4 acc[2] = {};
    for (int k0 = 0; k0 < DI; k0 += 32) {
        short8v af = *(const short8v*)&y_s[r][k0 + kh * 8];
        short8v bf[2];
#pragma unroll
        for (int jj = 0; jj < 2; ++jj)
            bf[jj] = *(const short8v*)&Wo[(size_t)(wave * 32 + jj * 16 + r) * DI + k0 + kh * 8];
#pragma unroll
        for (int jj = 0; jj < 2; ++jj)
            acc[jj] = __builtin_amdgcn_mfma_f32_16x16x32_bf16(af, bf[jj], acc[jj], 0, 0, 0);
    }
    __syncthreads();
#pragma unroll
    for (int jj = 0; jj < 2; ++jj)
#pragma unroll
        for (int rg = 0; rg < 4; ++rg) {
            size_t off = (size_t)(base + kh * 4 + rg) * DM + wave * 32 + jj * 16 + r;
            hout[off] += acc[jj][rg];
        }
}

__device__ __forceinline__ void dev_out(int t, int lane,
    const float* __restrict__ h, const float* __restrict__ ow, const float* __restrict__ ob,
    float* __restrict__ out) {
    float s = h[t * DM + lane] * ow[lane] + h[t * DM + lane + 64] * ow[lane + 64];
#pragma unroll
    for (int off = 32; off; off >>= 1) s += __shfl_xor(s, off);
    if (lane == 0) out[t] = s + ob[0];
}

// ---- fallback-only phase bodies (proven multi-launch path) ----

__device__ __forceinline__ void dev_ln_gemm1(int v, int wave, int lane,
    const float* __restrict__ h, const float* __restrict__ lw, const float* __restrict__ lb,
    const __hip_bfloat16* __restrict__ W, float* __restrict__ xz,
    __hip_bfloat16* As) {
    int tileM = v >> 2, tileN = v & 3;
    int mBase = tileM * 64, nBase = tileN * 128;
    for (int it = 0; it < 16; ++it) {
        int row = wave * 16 + it;
        int t = mBase + row;
        float v0 = h[t * DM + lane];
        float v1 = h[t * DM + lane + 64];
        float s = v0 + v1;
#pragma unroll
        for (int off = 32; off; off >>= 1) s += __shfl_xor(s, off);
        float mean = s * (1.f / 128.f);
        float d0 = v0 - mean, d1 = v1 - mean;
        float q = d0 * d0 + d1 * d1;
#pragma unroll
        for (int off = 32; off; off >>= 1) q += __shfl_xor(q, off);
        float rstd = rsqrtf(q * (1.f / 128.f) + 1e-5f);
        int sw = (row & 7) << 3;
        As[row * 128 + (lane ^ sw)]        = __float2bfloat16(d0 * rstd * lw[lane] + lb[lane]);
        As[row * 128 + ((lane + 64) ^ sw)] = __float2bfloat16(d1 * rstd * lw[lane + 64] + lb[lane + 64]);
    }
    __syncthreads();
    int r  = lane & 15;
    int kh = lane >> 4;
    f32x4 acc[4][2] = {};
    for (int k0 = 0; k0 < DM; k0 += 32) {
        short8v af[4], bf[2];
#pragma unroll
        for (int i = 0; i < 4; ++i) {
            int row = i * 16 + r;
            int cbk = (k0 >> 3) + kh;
            af[i] = *(const short8v*)&As[row * 128 + ((cbk ^ (row & 7)) << 3)];
        }
#pragma unroll
        for (int j = 0; j < 2; ++j)
            bf[j] = *(const short8v*)&W[(size_t)(nBase + wave * 32 + j * 16 + r) * DM + k0 + kh * 8];
#pragma unroll
        for (int i = 0; i < 4; ++i)
#pragma unroll
            for (int j = 0; j < 2; ++j)
                acc[i][j] = __builtin_amdgcn_mfma_f32_16x16x32_bf16(af[i], bf[j], acc[i][j], 0, 0, 0);
    }
#pragma unroll
    for (int i = 0; i < 4; ++i)
#pragma unroll
        for (int j = 0; j < 2; ++j)
#pragma unroll
            for (int rg = 0; rg < 4; ++rg) {
                size_t off = (size_t)(mBase + i * 16 + kh * 4 + rg) * (2 * DI)
                           + nBase + wave * 32 + j * 16 + r;
                xz[off] = acc[i][j][rg];
            }
    __syncthreads();
}

__device__ __forceinline__ void dev_conv_wx(int t, int lane,
    const float* __restrict__ xz, const float* __restrict__ cw, const float* __restrict__ cbs,
    const float* __restrict__ Wx, const float* __restrict__ Wdt, const float* __restrict__ bdt,
    float* __restrict__ xc, float* __restrict__ BC, float* __restrict__ delta) {
    int tl = t & (LL - 1);
    int b = t >> 11;
    float xv[4];
#pragma unroll
    for (int j = 0; j < 4; ++j) {
        int e = lane + 64 * j;
        float4 cw0 = *(const float4*)&cw[e * KC];
        float4 cw1 = *(const float4*)&cw[e * KC + 4];
        float wts[8] = {cw0.x, cw0.y, cw0.z, cw0.w, cw1.x, cw1.y, cw1.z, cw1.w};
        float acc = cbs[e];
#pragma unroll
        for (int k = 0; k < KC; ++k) {
            int pos = tl + k - (KC - 1);
            float v = (pos >= 0) ? xz[((size_t)(b * LL + pos) << 9) + e] : 0.f;
            acc = fmaf(v, wts[k], acc);
        }
        xv[j] = acc / (1.f + __expf(-acc));
        xc[((size_t)t << 8) + e] = xv[j];
    }
    float dt[8];
    float bcv = 0.f;
#pragma unroll
    for (int o = 0; o < 40; ++o) {
        const float* w = &Wx[o * DI];
        float s = xv[0] * w[lane];
        s = fmaf(xv[1], w[lane + 64], s);
        s = fmaf(xv[2], w[lane + 128], s);
        s = fmaf(xv[3], w[lane + 192], s);
#pragma unroll
        for (int off = 32; off; off >>= 1) s += __shfl_xor(s, off);
        if (o < 8) dt[o] = s;
        else if (lane == o - 8) bcv = s;
    }
    if (lane < 32) BC[((size_t)t << 5) + lane] = bcv;
#pragma unroll
    for (int j = 0; j < 4; ++j) {
        int e = lane + 64 * j;
        float s = bdt[e];
#pragma unroll
        for (int r = 0; r < 8; ++r) s = fmaf(dt[r], Wdt[e * 8 + r], s);
        delta[((size_t)t << 8) + e] = fmaxf(s, 0.f) + log1pf(__expf(-fabsf(s)));
    }
}

__device__ __forceinline__ void dev_scan1(int blk, int tid,
    const float* __restrict__ delta, const float* __restrict__ xc, const float* __restrict__ BC,
    const float* __restrict__ A_log,
    __hip_bfloat16* __restrict__ P, __hip_bfloat16* __restrict__ hend) {
    int eg = blk & 3;
    int c = (blk >> 2) & (NC - 1);
    int b = blk >> 9;
    int e = eg * 64 + (tid >> 2);
    int ng = tid & 3;
    float4 al = *(const float4*)&A_log[e * DS + 4 * ng];
    float Aen[4] = {-__expf(al.x), -__expf(al.y), -__expf(al.z), -__expf(al.w)};
    float h[4] = {}, Pl[4] = {1.f, 1.f, 1.f, 1.f};
    int base = b * LL + c * CT;
    const float* dp = delta + (size_t)base * DI + e;
    const float* up = xc + (size_t)base * DI + e;
    const float* bp = BC + (size_t)base * 32 + 4 * ng;
    for (int l0 = 0; l0 < CT; l0 += SU) {
        float d[SU], u[SU];
        float4 bm[SU];
#pragma unroll
        for (int j = 0; j < SU; ++j) {
            d[j]  = dp[(l0 + j) * DI];
            u[j]  = up[(l0 + j) * DI];
            bm[j] = *(const float4*)&bp[(l0 + j) * 32];
        }
#pragma unroll
        for (int j = 0; j < SU; ++j) {
            float du = d[j] * u[j];
            float a0 = __expf(d[j] * Aen[0]);
            float a1 = __expf(d[j] * Aen[1]);
            float a2 = __expf(d[j] * Aen[2]);
            float a3 = __expf(d[j] * Aen[3]);
            h[0] = fmaf(h[0], a0, du * bm[j].x);
            h[1] = fmaf(h[1], a1, du * bm[j].y);
            h[2] = fmaf(h[2], a2, du * bm[j].z);
            h[3] = fmaf(h[3], a3, du * bm[j].w);
            Pl[0] *= a0; Pl[1] *= a1; Pl[2] *= a2; Pl[3] *= a3;
        }
    }
    size_t oidx = (((size_t)(b * NC + c)) * DI + e) * DS + 4 * ng;
    store_bf16x4(&P[oidx], Pl[0], Pl[1], Pl[2], Pl[3]);
    store_bf16x4(&hend[oidx], h[0], h[1], h[2], h[3]);
}

__device__ __forceinline__ void dev_carry(int gtid,
    const __hip_bfloat16* __restrict__ P, const __hip_bfloat16* __restrict__ hend,
    __hip_bfloat16* __restrict__ hin) {
    int n = gtid & 15;
    int e = (gtid >> 4) & 255;
    int b = gtid >> 12;
    const size_t cs = (size_t)DI * DS;
    size_t idx0 = (((size_t)(b * NC)) * DI + e) * DS + n;
    float carry = 0.f;
    for (int c0 = 0; c0 < NC; c0 += 8) {
        float p[8], he[8];
#pragma unroll
        for (int j = 0; j < 8; ++j) {
            size_t idx = idx0 + (size_t)(c0 + j) * cs;
            p[j]  = __bfloat162float(P[idx]);
            he[j] = __bfloat162float(hend[idx]);
        }
#pragma unroll
        for (int j = 0; j < 8; ++j) {
            hin[idx0 + (size_t)(c0 + j) * cs] = __float2bfloat16(carry);
            carry = fmaf(p[j], carry, he[j]);
        }
    }
}

__device__ __forceinline__ void dev_scan3(int blk, int tid,
    const float* __restrict__ delta, const float* __restrict__ xc, const float* __restrict__ BC,
    const float* __restrict__ A_log, const __hip_bfloat16* __restrict__ hin,
    const float* __restrict__ xz,
    const float* __restrict__ Dsk, __hip_bfloat16* __restrict__ y) {
    int eg = blk & 3;
    int c = (blk >> 2) & (NC - 1);
    int b = blk >> 9;
    int e = eg * 64 + (tid >> 2);
    int ng = tid & 3;
    float4 al = *(const float4*)&A_log[e * DS + 4 * ng];
    float Aen[4] = {-__expf(al.x), -__expf(al.y), -__expf(al.z), -__expf(al.w)};
    float dsk = Dsk[e];
    float4 h4 = load_bf16x4(&hin[(((size_t)(b * NC + c)) * DI + e) * DS + 4 * ng]);
    float h[4] = {h4.x, h4.y, h4.z, h4.w};
    int base = b * LL + c * CT;
    const float* dp = delta + (size_t)base * DI + e;
    const float* up = xc + (size_t)base * DI + e;
    const float* bp = BC + (size_t)base * 32 + 4 * ng;
    const float* zp = xz + ((size_t)base << 9) + DI + e;
    __hip_bfloat16* yp = y + (size_t)base * DI + e;
    for (int l0 = 0; l0 < CT; l0 += SU) {
        float d[SU], u[SU], zv[SU];
        float4 bm[SU], cm[SU];
#pragma unroll
        for (int j = 0; j < SU; ++j) {
            d[j]  = dp[(l0 + j) * DI];
            u[j]  = up[(l0 + j) * DI];
            bm[j] = *(const float4*)&bp[(l0 + j) * 32];
            cm[j] = *(const float4*)&bp[(l0 + j) * 32 + 16];
            zv[j] = zp[(size_t)(l0 + j) << 9];
        }
#pragma unroll
        for (int j = 0; j < SU; ++j) {
            float du = d[j] * u[j];
            float a0 = __expf(d[j] * Aen[0]);
            float a1 = __expf(d[j] * Aen[1]);
            float a2 = __expf(d[j] * Aen[2]);
            float a3 = __expf(d[j] * Aen[3]);
            h[0] = fmaf(h[0], a0, du * bm[j].x);
            h[1] = fmaf(h[1], a1, du * bm[j].y);
            h[2] = fmaf(h[2], a2, du * bm[j].z);
            h[3] = fmaf(h[3], a3, du * bm[j].w);
            float yc = h[0] * cm[j].x;
            yc = fmaf(h[1], cm[j].y, yc);
            yc = fmaf(h[2], cm[j].z, yc);
            yc = fmaf(h[3], cm[j].w, yc);
            yc += __shfl_xor(yc, 1);
            yc += __shfl_xor(yc, 2);
            if (ng == 0) {
                float z = zv[j];
                float val = (yc + dsk * u[j]) * (z / (1.f + __expf(-z)));
                yp[(l0 + j) * DI] = __float2bfloat16(val);
            }
        }
    }
}

__device__ __forceinline__ void dev_gemm2(int v, int wave, int lane,
    const __hip_bfloat16* __restrict__ A, const __hip_bfloat16* __restrict__ W,
    float* __restrict__ C) {
    int mBase = v * 16;
    int r  = lane & 15;
    int kh = lane >> 4;
    f32x4 acc[2] = {};
    for (int k0 = 0; k0 < DI; k0 += 32) {
        short8v af = *(const short8v*)&A[(size_t)(mBase + r) * DI + k0 + kh * 8];
        short8v bf[2];
#pragma unroll
        for (int j = 0; j < 2; ++j)
            bf[j] = *(const short8v*)&W[(size_t)(wave * 32 + j * 16 + r) * DI + k0 + kh * 8];
#pragma unroll
        for (int j = 0; j < 2; ++j)
            acc[j] = __builtin_amdgcn_mfma_f32_16x16x32_bf16(af, bf[j], acc[j], 0, 0, 0);
    }
#pragma unroll
    for (int j = 0; j < 2; ++j)
#pragma unroll
        for (int rg = 0; rg < 4; ++rg) {
            size_t off = (size_t)(mBase + kh * 4 + rg) * DM + wave * 32 + j * 16 + r;
            C[off] += acc[j][rg];
        }
}

// ================= cooperative mega-kernel =================

struct MegaArgs {
    const float *x, *pcw, *pcb, *ln_w, *ln_b, *conv_w, *conv_b;
    const float *W_x, *W_dt, *b_dt, *A_log, *D_skip, *W_in, *W_out, *out_w, *out_b;
    float *h, *out;
    __hip_bfloat16 *P, *hend, *hincl, *wi_bf, *wo_bf;
    int *flags;
};

// LDS: union(As 8K + xi 16K = 24K, y_s 8.25K) + xc 16K + dl 16K + bc 2K + z 8K + hin 8K = 74KB -> 2/CU
__global__ __launch_bounds__(256, 2) void k_mega(MegaArgs a) {
    __shared__ union {
        struct {
            __hip_bfloat16 As[32 * 128];
            __hip_bfloat16 xi[32][DI];
        } pa;
        __hip_bfloat16 y_s[CT][DI + 8];
    } u;
    __shared__ float xc_s[CT][DI];
    __shared__ float dl_s[CT][DI];
    __shared__ float bc_s[CT][32];
    __shared__ __hip_bfloat16 z_s[CT][DI];
    __shared__ __hip_bfloat16 hin_s[DI][DS];
    cg::grid_group g = cg::this_grid();
    int bid = blockIdx.x, tid = threadIdx.x;
    int nb = gridDim.x;
    int wave = tid >> 6, lane = tid & 63;

    for (int v = bid * 256 + tid; v < NCHUNK; v += nb * 256) a.flags[v] = 0;
    for (int v = bid; v < (BB * LL * DM) / 256; v += nb)
        dev_preconv(v * 256 + tid, a.x, a.pcw, a.pcb, a.h, a.W_in, a.W_out, a.wi_bf, a.wo_bf);
    g.sync();

    for (int blk = 0; blk < NB; ++blk) {
        dev_phaseA(bid, tid, blk + 1, a.h, a.ln_w + blk * DM, a.ln_b + blk * DM,
                   a.wi_bf + (size_t)blk * 2 * DI * DM,
                   a.conv_w + (size_t)blk * DI * KC, a.conv_b + blk * DI,
                   a.W_x + (size_t)blk * 40 * DI, a.W_dt + (size_t)blk * DI * DTR,
                   a.b_dt + blk * DI, a.A_log + (size_t)blk * DI * DS,
                   a.P, a.hend, a.hincl, a.flags,
                   u.pa.As, u.pa.xi, xc_s, dl_s, bc_s, z_s, hin_s);
        dev_fusedB(bid, tid, a.A_log + (size_t)blk * DI * DS,
                   a.D_skip + blk * DI, a.wo_bf + (size_t)blk * DM * DI, a.h,
                   xc_s, dl_s, bc_s, z_s, hin_s, u.y_s);
        g.sync();
    }

    for (int v = bid; v < BL / 4; v += nb)
        dev_out(v * 4 + wave, lane, a.h, a.out_w, a.out_b, a.out);
}

// ================= fallback wrappers (multi-launch path) =================

__global__ void w_preconv(const float* x, const float* w, const float* bias, float* h,
                          const float* Wi, const float* Wo,
                          __hip_bfloat16* wi, __hip_bfloat16* wo) {
    dev_preconv(blockIdx.x * 256 + threadIdx.x, x, w, bias, h, Wi, Wo, wi, wo);
}
__global__ __launch_bounds__(256) void w_ln_gemm1(const float* h, const float* lw, const float* lb,
                                                  const __hip_bfloat16* W, float* xz) {
    __shared__ __hip_bfloat16 As[64 * 128];
    dev_ln_gemm1(blockIdx.x, threadIdx.x >> 6, threadIdx.x & 63, h, lw, lb, W, xz, As);
}
__global__ __launch_bounds__(256) void w_conv_wx(const float* xz, const float* cw, const float* cbs,
                                                 const float* Wx, const float* Wdt, const float* bdt,
                                                 float* xc, float* BC, float* delta) {
    dev_conv_wx(blockIdx.x * 4 + (threadIdx.x >> 6), threadIdx.x & 63,
                xz, cw, cbs, Wx, Wdt, bdt, xc, BC, delta);
}
__global__ __launch_bounds__(256) void w_scan1(const float* delta, const float* xc, const float* BC,
                                               const float* A_log,
                                               __hip_bfloat16* P, __hip_bfloat16* hend) {
    dev_scan1(blockIdx.x, threadIdx.x, delta, xc, BC, A_log, P, hend);
}
__global__ void w_carry(const __hip_bfloat16* P, const __hip_bfloat16* hend, __hip_bfloat16* hin) {
    dev_carry(blockIdx.x * 256 + threadIdx.x, P, hend, hin);
}
__global__ __launch_bounds__(256) void w_scan3(const float* delta, const float* xc, const float* BC,
                                               const float* A_log, const __hip_bfloat16* hin,
                                               const float* xz,
                                               const float* Dsk, __hip_bfloat16* y) {
    dev_scan3(blockIdx.x, threadIdx.x, delta, xc, BC, A_log, hin, xz, Dsk, y);
}
__global__ __launch_bounds__(256) void w_gemm2(const __hip_bfloat16* A, const __hip_bfloat16* W,
                                               float* C) {
    dev_gemm2(blockIdx.x, threadIdx.x >> 6, threadIdx.x & 63, A, W, C);
}
__global__ void w_out(const float* h, const float* ow, const float* ob, float* out) {
    dev_out(blockIdx.x * 4 + (threadIdx.x >> 6), threadIdx.x & 63, h, ow, ob, out);
}

extern "C" void kernel_launch(void* const* d_in, const int* in_sizes, int n_in,
                              void* d_out, int out_size, void* d_ws, size_t ws_size,
                              hipStream_t stream) {
    (void)in_sizes; (void)n_in; (void)out_size; (void)ws_size;
    const float* x      = (const float*)d_in[0];
    const float* pcw    = (const float*)d_in[1];
    const float* pcb    = (const float*)d_in[2];
    const float* ln_w   = (const float*)d_in[3];
    const float* ln_b   = (const float*)d_in[4];
    const float* W_in   = (const float*)d_in[5];
    const float* conv_w = (const float*)d_in[6];
    const float* conv_b = (const float*)d_in[7];
    const float* W_x    = (const float*)d_in[8];
    const float* W_dt   = (const float*)d_in[9];
    const float* b_dt   = (const float*)d_in[10];
    const float* A_log  = (const float*)d_in[11];
    const float* D_skip = (const float*)d_in[12];
    const float* W_out  = (const float*)d_in[13];
    const float* out_w  = (const float*)d_in[14];
    const float* out_b  = (const float*)d_in[15];

    const size_t SCAN_N = (size_t)BB * NC * DI * DS;
    float* ws    = (float*)d_ws;
    float* h     = ws;                              // BL*DM
    float* xz    = h     + (size_t)BL * DM;         // BL*512 (fallback only)
    float* xc    = xz    + (size_t)BL * 2 * DI;     // BL*256 (fallback only)
    float* BC    = xc    + (size_t)BL * DI;         // BL*32  (fallback only)
    float* delta = BC    + (size_t)BL * 2 * DS;     // BL*256 (fallback only)
    __hip_bfloat16* P     = (__hip_bfloat16*)(delta + (size_t)BL * DI);
    __hip_bfloat16* hend  = P + SCAN_N;
    __hip_bfloat16* hin   = hend + SCAN_N;                      // fallback only
    __hip_bfloat16* hincl = hin + SCAN_N;                       // mega only
    __hip_bfloat16* y_bf  = hincl + SCAN_N;                     // BL*DI (fallback only)
    __hip_bfloat16* wi_bf = y_bf + (size_t)BL * DI;             // NB*512*128
    __hip_bfloat16* wo_bf = wi_bf + (size_t)NB * 2 * DI * DM;   // NB*128*256
    int* flags = (int*)(wo_bf + (size_t)NB * DM * DI);          // NCHUNK ints

    int dev = 0;
    (void)hipGetDevice(&dev);
    int coopAttr = 0;
    (void)hipDeviceGetAttribute(&coopAttr, hipDeviceAttributeCooperativeLaunch, dev);
    int numCU = 0;
    (void)hipDeviceGetAttribute(&numCU, hipDeviceAttributeMultiprocessorCount, dev);
    int maxBpCU = 0;
    (void)hipOccupancyMaxActiveBlocksPerMultiprocessor(&maxBpCU, k_mega, 256, 0);
    int grid = maxBpCU * numCU;
    if (grid > NCHUNK) grid = NCHUNK;

    bool launched = false;
    if (coopAttr && grid == NCHUNK) {   // lookback requires ALL chunks resident
        MegaArgs ma = {x, pcw, pcb, ln_w, ln_b, conv_w, conv_b,
                       W_x, W_dt, b_dt, A_log, D_skip, W_in, W_out, out_w, out_b,
                       h, (float*)d_out,
                       P, hend, hincl, wi_bf, wo_bf, flags};
        void* kp[] = {&ma};
        hipError_t e = hipLaunchCooperativeKernel((void*)k_mega, dim3(grid), dim3(256), kp, 0, stream);
        launched = (e == hipSuccess);
        if (!launched) (void)hipGetLastError();
    }

    if (!launched) {
        // -------- fallback: proven multi-launch path --------
        w_preconv<<<(BB * LL * DM) / 256, 256, 0, stream>>>(x, pcw, pcb, h, W_in, W_out, wi_bf, wo_bf);
        for (int blk = 0; blk < NB; ++blk) {
            w_ln_gemm1<<<512, 256, 0, stream>>>(
                h, ln_w + blk * DM, ln_b + blk * DM, wi_bf + (size_t)blk * 2 * DI * DM, xz);
            w_conv_wx<<<BL / 4, 256, 0, stream>>>(
                xz, conv_w + (size_t)blk * DI * KC, conv_b + blk * DI,
                W_x + (size_t)blk * 40 * DI, W_dt + (size_t)blk * DI * DTR,
                b_dt + blk * DI, xc, BC, delta);
            w_scan1<<<BB * NC * 4, 256, 0, stream>>>(
                delta, xc, BC, A_log + (size_t)blk * DI * DS, P, hend);
            w_carry<<<(BB * DI * DS) / 256, 256, 0, stream>>>(P, hend, hin);
            w_scan3<<<BB * NC * 4, 256, 0, stream>>>(
                delta, xc, BC, A_log + (size_t)blk * DI * DS, hin, xz, D_skip + blk * DI, y_bf);
            w_gemm2<<<BL / 16, 256, 0, stream>>>(y_bf, wo_bf + (size_t)blk * DM * DI, h);
        }
        w_out<<<BL / 4, 256, 0, stream>>>(h, out_w, out_b, (float*)d_out);
    }
}

// Round 16
// 554.133 us; speedup vs baseline: 1.0152x; 1.0152x over previous
//
#include <hip/hip_runtime.h>
#include <hip/hip_bf16.h>
#include <hip/hip_cooperative_groups.h>
#include <math.h>

namespace cg = cooperative_groups;

#define BB 4
#define LL 2048
#define DM 128
#define DI 256
#define DS 16
#define DTR 8
#define NB 6
#define KPRE 7
#define KC 8
#define NC 128      // chunks per sequence
#define CT 16       // chunk length (NC*CT == LL)
#define NCHUNK (BB*NC)   // 512 == cooperative grid
#define BL (BB*LL)  // 8192 tokens
#define SU 4        // scan unroll factor (fallback scans)

typedef __attribute__((ext_vector_type(8))) short short8v;
typedef __attribute__((ext_vector_type(4))) short short4v;
typedef __attribute__((ext_vector_type(4))) float f32x4;

// ---- bf16 pack/unpack helpers ----
__device__ __forceinline__ void store_bf16x4(__hip_bfloat16* p, float a, float b, float c, float d) {
    __hip_bfloat16 t[4] = {__float2bfloat16(a), __float2bfloat16(b),
                           __float2bfloat16(c), __float2bfloat16(d)};
    *(short4v*)p = *(const short4v*)t;
}
__device__ __forceinline__ float4 load_bf16x4(const __hip_bfloat16* p) {
    short4v raw = *(const short4v*)p;
    const __hip_bfloat16* t = (const __hip_bfloat16*)&raw;
    return make_float4(__bfloat162float(t[0]), __bfloat162float(t[1]),
                       __bfloat162float(t[2]), __bfloat162float(t[3]));
}
__device__ __forceinline__ void load_bf16x8(const __hip_bfloat16* p, float* o) {
    short8v a = *(const short8v*)p;
    const __hip_bfloat16* ta = (const __hip_bfloat16*)&a;
#pragma unroll
    for (int i = 0; i < 8; ++i) o[i] = __bfloat162float(ta[i]);
}
__device__ __forceinline__ void store_bf16x8(__hip_bfloat16* p, const float* v) {
    __hip_bfloat16 t[8];
#pragma unroll
    for (int i = 0; i < 8; ++i) t[i] = __float2bfloat16(v[i]);
    *(short8v*)p = *(const short8v*)t;
}

// ================= mega phase bodies (512-thread blocks) =================

__device__ __forceinline__ void dev_preconv(int idx,
    const float* __restrict__ x, const float* __restrict__ w, const float* __restrict__ bias,
    float* __restrict__ h, const float* __restrict__ Wi, const float* __restrict__ Wo,
    const float* __restrict__ Wxf,
    __hip_bfloat16* __restrict__ wi, __hip_bfloat16* __restrict__ wo,
    __hip_bfloat16* __restrict__ wx) {
    int d = idx & (DM - 1);
    int l = (idx >> 7) & (LL - 1);
    int b = idx >> 18;
    float acc = bias[d];
#pragma unroll
    for (int k = 0; k < KPRE; ++k) {
        int pos = l + k - 3;
        float xv = (pos >= 0 && pos < LL) ? x[b * LL + pos] : 0.f;
        acc = fmaf(xv, w[d * KPRE + k], acc);
    }
    h[idx] = 0.5f * acc * (1.f + erff(acc * 0.70710678118654752f));
    if (idx < NB * 2 * DI * DM) wi[idx] = __float2bfloat16(Wi[idx]);
    if (idx < NB * DM * DI)     wo[idx] = __float2bfloat16(Wo[idx]);
    if (idx < NB * 40 * DI)     wx[idx] = __float2bfloat16(Wxf[idx]);
}

// ---- phase A: LN + GEMM1(LDS) + conv + MFMA-Wx + delta + scan1 + lookback ----
__device__ __forceinline__ void dev_phaseA(int chunk, int tid, int epoch,
    const float* __restrict__ h, const float* __restrict__ lw, const float* __restrict__ lb,
    const __hip_bfloat16* __restrict__ Wi, const __hip_bfloat16* __restrict__ Wx,
    const float* __restrict__ cw, const float* __restrict__ cbs,
    const float* __restrict__ Wdt, const float* __restrict__ bdt,
    const float* __restrict__ A_log,
    __hip_bfloat16* __restrict__ Pst, __hip_bfloat16* __restrict__ hend,
    __hip_bfloat16* __restrict__ hincl, int* __restrict__ flags,
    __hip_bfloat16* As, __hip_bfloat16 (*xi_s)[DI],
    __hip_bfloat16 (*xcb_s)[DI], float (*dl_s)[DI], float (*bc_s)[32],
    __hip_bfloat16 (*z_s)[DI], __hip_bfloat16 (*hin_s)[DS], float (*dbl_s)[48]) {
    int c = chunk & (NC - 1);
    int b = chunk >> 7;                 // NC=128
    int wave = tid >> 6, lane = tid & 63;
    // ---- LN: 32 rows over 8 waves (4 rows/wave); rows with tl<0 -> zeros ----
    for (int it = 0; it < 4; ++it) {
        int lr = wave * 4 + it;
        int tl = c * CT + lr - 16;
        int sw = (lr & 7) << 3;
        if (tl >= 0) {
            int t = b * LL + tl;
            float v0 = h[t * DM + lane];
            float v1 = h[t * DM + lane + 64];
            float s = v0 + v1;
#pragma unroll
            for (int off = 32; off; off >>= 1) s += __shfl_xor(s, off);
            float mean = s * (1.f / 128.f);
            float d0 = v0 - mean, d1 = v1 - mean;
            float q = d0 * d0 + d1 * d1;
#pragma unroll
            for (int off = 32; off; off >>= 1) q += __shfl_xor(q, off);
            float rstd = rsqrtf(q * (1.f / 128.f) + 1e-5f);
            As[lr * 128 + (lane ^ sw)]        = __float2bfloat16(d0 * rstd * lw[lane] + lb[lane]);
            As[lr * 128 + ((lane + 64) ^ sw)] = __float2bfloat16(d1 * rstd * lw[lane + 64] + lb[lane + 64]);
        } else {
            As[lr * 128 + (lane ^ sw)]        = __float2bfloat16(0.f);
            As[lr * 128 + ((lane + 64) ^ sw)] = __float2bfloat16(0.f);
        }
    }
    __syncthreads();
    // ---- GEMM1: 8 waves x 64 cols. waves 0-3 -> xi (rows 0-31); waves 4-7 -> z (rows 16-31) ----
    {
        int r = lane & 15, kh = lane >> 4;
        short8v af[2][4];
#pragma unroll
        for (int mf = 0; mf < 2; ++mf)
#pragma unroll
            for (int k = 0; k < 4; ++k) {
                int row = mf * 16 + r;
                int cbk = k * 4 + kh;
                af[mf][k] = *(const short8v*)&As[row * 128 + ((cbk ^ (row & 7)) << 3)];
            }
        if (wave < 4) {
            int nBase = wave * 64;
            for (int nf = 0; nf < 4; ++nf) {
                short8v bfr[4];
#pragma unroll
                for (int k = 0; k < 4; ++k)
                    bfr[k] = *(const short8v*)&Wi[(size_t)(nBase + nf * 16 + r) * DM + k * 32 + kh * 8];
                f32x4 acc0 = {}, acc1 = {};
#pragma unroll
                for (int k = 0; k < 4; ++k) {
                    acc0 = __builtin_amdgcn_mfma_f32_16x16x32_bf16(af[0][k], bfr[k], acc0, 0, 0, 0);
                    acc1 = __builtin_amdgcn_mfma_f32_16x16x32_bf16(af[1][k], bfr[k], acc1, 0, 0, 0);
                }
#pragma unroll
                for (int rg = 0; rg < 4; ++rg) {
                    xi_s[kh * 4 + rg][nBase + nf * 16 + r]      = __float2bfloat16(acc0[rg]);
                    xi_s[16 + kh * 4 + rg][nBase + nf * 16 + r] = __float2bfloat16(acc1[rg]);
                }
            }
        } else {
            int zBase = (wave - 4) * 64;
            for (int nf = 0; nf < 4; ++nf) {
                short8v bfr[4];
#pragma unroll
                for (int k = 0; k < 4; ++k)
                    bfr[k] = *(const short8v*)&Wi[(size_t)(256 + zBase + nf * 16 + r) * DM + k * 32 + kh * 8];
                f32x4 acc1 = {};
#pragma unroll
                for (int k = 0; k < 4; ++k)
                    acc1 = __builtin_amdgcn_mfma_f32_16x16x32_bf16(af[1][k], bfr[k], acc1, 0, 0, 0);
#pragma unroll
                for (int rg = 0; rg < 4; ++rg)
                    z_s[kh * 4 + rg][zBase + nf * 16 + r] = __float2bfloat16(acc1[rg]);
            }
        }
    }
    __syncthreads();
    // ---- conv + SiLU -> xcb (bf16): 8 waves x 2 tokens ----
    for (int i = 0; i < 2; ++i) {
        int lt = wave * 2 + i;
#pragma unroll
        for (int j = 0; j < 4; ++j) {
            int e = lane + 64 * j;
            float4 c0 = *(const float4*)&cw[e * KC];
            float4 c1 = *(const float4*)&cw[e * KC + 4];
            float wts[8] = {c0.x, c0.y, c0.z, c0.w, c1.x, c1.y, c1.z, c1.w};
            float acc = cbs[e];
#pragma unroll
            for (int k = 0; k < KC; ++k)
                acc = fmaf(__bfloat162float(xi_s[lt + 9 + k][e]), wts[k], acc);
            float sv = acc / (1.f + __expf(-acc));
            xcb_s[lt][e] = __float2bfloat16(sv);
        }
    }
    __syncthreads();
    // ---- Wx projection via MFMA: [16 tok x 256] x [48 out x 256]^T, waves 0-2 ----
    if (wave < 3) {
        int r = lane & 15, kh = lane >> 4;
        f32x4 acc = {};
        for (int k0 = 0; k0 < DI; k0 += 32) {
            short8v a = *(const short8v*)&xcb_s[r][k0 + kh * 8];
            int o = wave * 16 + r;
            short8v w8;
            if (o < 40) w8 = *(const short8v*)&Wx[(size_t)o * DI + k0 + kh * 8];
            else { short z[8] = {}; w8 = *(const short8v*)z; }
            acc = __builtin_amdgcn_mfma_f32_16x16x32_bf16(a, w8, acc, 0, 0, 0);
        }
#pragma unroll
        for (int rg = 0; rg < 4; ++rg)
            dbl_s[kh * 4 + rg][wave * 16 + r] = acc[rg];
    }
    __syncthreads();
    // ---- bc fill + delta ----
    {
        int l = tid >> 5, i = tid & 31;
        bc_s[l][i] = dbl_s[l][8 + i];
    }
    {
        int e = tid & 255, th = tid >> 8;
        for (int l = th * 8; l < th * 8 + 8; ++l) {
            float s = bdt[e];
#pragma unroll
            for (int r = 0; r < 8; ++r) s = fmaf(dbl_s[l][r], Wdt[e * 8 + r], s);
            dl_s[l][e] = fmaxf(s, 0.f) + log1pf(__expf(-fabsf(s)));
        }
    }
    __syncthreads();
    // ---- chunk-local scan1: thread = (e, half); 2 ng chains each ----
    int e = tid >> 1, half = tid & 1;
    {
        float d16[CT], u16[CT];
#pragma unroll
        for (int l = 0; l < CT; ++l) { d16[l] = dl_s[l][e]; u16[l] = __bfloat162float(xcb_s[l][e]); }
        for (int ngi = 0; ngi < 2; ++ngi) {
            int ng = half * 2 + ngi;
            float4 al = *(const float4*)&A_log[e * DS + 4 * ng];
            float Aen[4] = {-__expf(al.x), -__expf(al.y), -__expf(al.z), -__expf(al.w)};
            float hh[4] = {}, Pl[4] = {1.f, 1.f, 1.f, 1.f};
#pragma unroll
            for (int l = 0; l < CT; ++l) {
                float du = d16[l] * u16[l];
                float4 bm = *(const float4*)&bc_s[l][4 * ng];
                float a0 = __expf(d16[l] * Aen[0]);
                float a1 = __expf(d16[l] * Aen[1]);
                float a2 = __expf(d16[l] * Aen[2]);
                float a3 = __expf(d16[l] * Aen[3]);
                hh[0] = fmaf(hh[0], a0, du * bm.x);
                hh[1] = fmaf(hh[1], a1, du * bm.y);
                hh[2] = fmaf(hh[2], a2, du * bm.z);
                hh[3] = fmaf(hh[3], a3, du * bm.w);
                Pl[0] *= a0; Pl[1] *= a1; Pl[2] *= a2; Pl[3] *= a3;
            }
            size_t oidx = (((size_t)(b * NC + c)) * DI + e) * DS + 4 * ng;
            store_bf16x4(&Pst[oidx], Pl[0], Pl[1], Pl[2], Pl[3]);
            store_bf16x4(&hend[oidx], hh[0], hh[1], hh[2], hh[3]);
        }
    }
    // ---- publish local state ----
    __threadfence();
    __syncthreads();
    if (tid == 0)
        __hip_atomic_store(&flags[b * NC + c], 2 * epoch,
                           __ATOMIC_RELEASE, __HIP_MEMORY_SCOPE_AGENT);
    // ---- decoupled lookback: thread (e, half) owns 8 n's ----
    float hacc[8], Pacc[8];
#pragma unroll
    for (int n = 0; n < 8; ++n) { hacc[n] = 0.f; Pacc[n] = 1.f; }
    int j = c - 1;
    while (j >= 0) {
        int f1;
        do {
            f1 = __hip_atomic_load(&flags[b * NC + j], __ATOMIC_ACQUIRE, __HIP_MEMORY_SCOPE_AGENT);
            if (f1 < 2 * epoch) __builtin_amdgcn_s_sleep(2);
        } while (f1 < 2 * epoch);
        size_t bj = (((size_t)(b * NC + j)) * DI + e) * DS + half * 8;
        if (f1 > 2 * epoch) {            // j holds inclusive prefix
            float hi[8]; load_bf16x8(&hincl[bj], hi);
#pragma unroll
            for (int n = 0; n < 8; ++n) hacc[n] = fmaf(Pacc[n], hi[n], hacc[n]);
            break;
        }
        float pj[8], he[8];
        load_bf16x8(&Pst[bj], pj);
        load_bf16x8(&hend[bj], he);
#pragma unroll
        for (int n = 0; n < 8; ++n) { hacc[n] = fmaf(Pacc[n], he[n], hacc[n]); Pacc[n] *= pj[n]; }
        --j;
    }
    // ---- own inclusive publish + hin to LDS ----
    {
        size_t bcx = (((size_t)(b * NC + c)) * DI + e) * DS + half * 8;
        float pc[8], hc[8];
        load_bf16x8(&Pst[bcx], pc);
        load_bf16x8(&hend[bcx], hc);
#pragma unroll
        for (int n = 0; n < 8; ++n) {
            hin_s[e][half * 8 + n] = __float2bfloat16(hacc[n]);
            hc[n] = fmaf(pc[n], hacc[n], hc[n]);
        }
        store_bf16x8(&hincl[bcx], hc);
    }
    __threadfence();
    __syncthreads();
    if (tid == 0)
        __hip_atomic_store(&flags[b * NC + c], 2 * epoch + 1,
                           __ATOMIC_RELEASE, __HIP_MEMORY_SCOPE_AGENT);
}

// ---- phase B: scan3 (hin LDS) + gate (z LDS) -> y LDS -> gemm2 ----
__device__ __forceinline__ void dev_fusedB(int chunk, int tid,
    const float* __restrict__ A_log, const float* __restrict__ Dsk,
    const __hip_bfloat16* __restrict__ Wo, float* __restrict__ hout,
    const __hip_bfloat16 (*xcb_s)[DI], const float (*dl_s)[DI], const float (*bc_s)[32],
    const __hip_bfloat16 (*z_s)[DI], const __hip_bfloat16 (*hin_s)[DS],
    __hip_bfloat16 (*y_s)[DI + 8]) {
    int c = chunk & (NC - 1);
    int b = chunk >> 7;
    int base = b * LL + c * CT;
    int e = tid >> 1, half = tid & 1;
    float d16[CT], u16[CT], yacc[CT];
    float dsk = Dsk[e];
#pragma unroll
    for (int l = 0; l < CT; ++l) {
        d16[l] = dl_s[l][e];
        u16[l] = __bfloat162float(xcb_s[l][e]);
        yacc[l] = half ? 0.f : dsk * u16[l];
    }
    for (int ngi = 0; ngi < 2; ++ngi) {
        int ng = half * 2 + ngi;
        float4 al = *(const float4*)&A_log[e * DS + 4 * ng];
        float Aen[4] = {-__expf(al.x), -__expf(al.y), -__expf(al.z), -__expf(al.w)};
        float hh[4] = {__bfloat162float(hin_s[e][4 * ng]),
                       __bfloat162float(hin_s[e][4 * ng + 1]),
                       __bfloat162float(hin_s[e][4 * ng + 2]),
                       __bfloat162float(hin_s[e][4 * ng + 3])};
#pragma unroll
        for (int l = 0; l < CT; ++l) {
            float du = d16[l] * u16[l];
            float4 bm = *(const float4*)&bc_s[l][4 * ng];
            float4 cm = *(const float4*)&bc_s[l][16 + 4 * ng];
            float a0 = __expf(d16[l] * Aen[0]);
            float a1 = __expf(d16[l] * Aen[1]);
            float a2 = __expf(d16[l] * Aen[2]);
            float a3 = __expf(d16[l] * Aen[3]);
            hh[0] = fmaf(hh[0], a0, du * bm.x);
            hh[1] = fmaf(hh[1], a1, du * bm.y);
            hh[2] = fmaf(hh[2], a2, du * bm.z);
            hh[3] = fmaf(hh[3], a3, du * bm.w);
            float p = hh[0] * cm.x;
            p = fmaf(hh[1], cm.y, p);
            p = fmaf(hh[2], cm.z, p);
            p = fmaf(hh[3], cm.w, p);
            yacc[l] += p;
        }
    }
#pragma unroll
    for (int l = 0; l < CT; ++l) {
        float full = yacc[l] + __shfl_xor(yacc[l], 1);
        if (half == 0) {
            float z = __bfloat162float(z_s[l][e]);
            y_s[l][e] = __float2bfloat16(full * (z / (1.f + __expf(-z))));
        }
    }
    __syncthreads();
    // gemm2: 16 rows x 128 cols, K=256; 8 waves x 16 cols
    int wave = tid >> 6, lane = tid & 63;
    int r  = lane & 15;
    int kh = lane >> 4;
    f32x4 acc = {};
    for (int k0 = 0; k0 < DI; k0 += 32) {
        short8v af = *(const short8v*)&y_s[r][k0 + kh * 8];
        short8v bf = *(const short8v*)&Wo[(size_t)(wave * 16 + r) * DI + k0 + kh * 8];
        acc = __builtin_amdgcn_mfma_f32_16x16x32_bf16(af, bf, acc, 0, 0, 0);
    }
    __syncthreads();   // y_s aliases As/xi_s; make reuse safe
#pragma unroll
    for (int rg = 0; rg < 4; ++rg) {
        size_t off = (size_t)(base + kh * 4 + rg) * DM + wave * 16 + r;
        hout[off] += acc[rg];
    }
}

__device__ __forceinline__ void dev_out(int t, int lane,
    const float* __restrict__ h, const float* __restrict__ ow, const float* __restrict__ ob,
    float* __restrict__ out) {
    float s = h[t * DM + lane] * ow[lane] + h[t * DM + lane + 64] * ow[lane + 64];
#pragma unroll
    for (int off = 32; off; off >>= 1) s += __shfl_xor(s, off);
    if (lane == 0) out[t] = s + ob[0];
}

// ================= cooperative mega-kernel =================

struct MegaArgs {
    const float *x, *pcw, *pcb, *ln_w, *ln_b, *conv_w, *conv_b;
    const float *W_x, *W_dt, *b_dt, *A_log, *D_skip, *W_in, *W_out, *out_w, *out_b;
    float *h, *out;
    __hip_bfloat16 *P, *hend, *hincl, *wi_bf, *wo_bf, *wx_bf;
    int *flags;
};

// LDS: union(As 8K + xi 16K = 24K, y_s 8.25K) + xcb 8K + dl 16K + bc 2K + z 8K + hin 8K + dbl 3K = 69KB
__global__ __launch_bounds__(512, 2) void k_mega(MegaArgs a) {
    __shared__ union {
        struct {
            __hip_bfloat16 As[32 * 128];
            __hip_bfloat16 xi[32][DI];
        } pa;
        __hip_bfloat16 y_s[CT][DI + 8];
    } u;
    __shared__ __hip_bfloat16 xcb_s[CT][DI];
    __shared__ float dl_s[CT][DI];
    __shared__ float bc_s[CT][32];
    __shared__ __hip_bfloat16 z_s[CT][DI];
    __shared__ __hip_bfloat16 hin_s[DI][DS];
    __shared__ float dbl_s[CT][48];
    cg::grid_group g = cg::this_grid();
    int bid = blockIdx.x, tid = threadIdx.x;
    int nb = gridDim.x;
    int wave = tid >> 6, lane = tid & 63;

    for (int v = bid * 512 + tid; v < NCHUNK; v += nb * 512) a.flags[v] = 0;
    for (int v = bid; v < (BB * LL * DM) / 512; v += nb)
        dev_preconv(v * 512 + tid, a.x, a.pcw, a.pcb, a.h, a.W_in, a.W_out, a.W_x,
                    a.wi_bf, a.wo_bf, a.wx_bf);
    g.sync();

    for (int blk = 0; blk < NB; ++blk) {
        dev_phaseA(bid, tid, blk + 1, a.h, a.ln_w + blk * DM, a.ln_b + blk * DM,
                   a.wi_bf + (size_t)blk * 2 * DI * DM, a.wx_bf + (size_t)blk * 40 * DI,
                   a.conv_w + (size_t)blk * DI * KC, a.conv_b + blk * DI,
                   a.W_dt + (size_t)blk * DI * DTR, a.b_dt + blk * DI,
                   a.A_log + (size_t)blk * DI * DS,
                   a.P, a.hend, a.hincl, a.flags,
                   u.pa.As, u.pa.xi, xcb_s, dl_s, bc_s, z_s, hin_s, dbl_s);
        dev_fusedB(bid, tid, a.A_log + (size_t)blk * DI * DS,
                   a.D_skip + blk * DI, a.wo_bf + (size_t)blk * DM * DI, a.h,
                   xcb_s, dl_s, bc_s, z_s, hin_s, u.y_s);
        g.sync();
    }

    for (int v = bid; v < BL / 8; v += nb)
        dev_out(v * 8 + wave, lane, a.h, a.out_w, a.out_b, a.out);
}

// ================= fallback: proven multi-launch path (256-thread kernels) =================

__global__ void w_preconv(const float* x, const float* w, const float* bias, float* h,
                          const float* Wi, const float* Wo, const float* Wxf,
                          __hip_bfloat16* wi, __hip_bfloat16* wo, __hip_bfloat16* wx) {
    int idx = blockIdx.x * 256 + threadIdx.x;
    int d = idx & (DM - 1);
    int l = (idx >> 7) & (LL - 1);
    int b = idx >> 18;
    float acc = bias[d];
#pragma unroll
    for (int k = 0; k < KPRE; ++k) {
        int pos = l + k - 3;
        float xv = (pos >= 0 && pos < LL) ? x[b * LL + pos] : 0.f;
        acc = fmaf(xv, w[d * KPRE + k], acc);
    }
    h[idx] = 0.5f * acc * (1.f + erff(acc * 0.70710678118654752f));
    if (idx < NB * 2 * DI * DM) wi[idx] = __float2bfloat16(Wi[idx]);
    if (idx < NB * DM * DI)     wo[idx] = __float2bfloat16(Wo[idx]);
    if (idx < NB * 40 * DI)     wx[idx] = __float2bfloat16(Wxf[idx]);
}

__global__ __launch_bounds__(256) void w_ln_gemm1(const float* __restrict__ h,
    const float* __restrict__ lw, const float* __restrict__ lb,
    const __hip_bfloat16* __restrict__ W, float* __restrict__ xz) {
    __shared__ __hip_bfloat16 As[64 * 128];
    int v = blockIdx.x, wave = threadIdx.x >> 6, lane = threadIdx.x & 63;
    int tileM = v >> 2, tileN = v & 3;
    int mBase = tileM * 64, nBase = tileN * 128;
    for (int it = 0; it < 16; ++it) {
        int row = wave * 16 + it;
        int t = mBase + row;
        float v0 = h[t * DM + lane];
        float v1 = h[t * DM + lane + 64];
        float s = v0 + v1;
#pragma unroll
        for (int off = 32; off; off >>= 1) s += __shfl_xor(s, off);
        float mean = s * (1.f / 128.f);
        float d0 = v0 - mean, d1 = v1 - mean;
        float q = d0 * d0 + d1 * d1;
#pragma unroll
        for (int off = 32; off; off >>= 1) q += __shfl_xor(q, off);
        float rstd = rsqrtf(q * (1.f / 128.f) + 1e-5f);
        int sw = (row & 7) << 3;
        As[row * 128 + (lane ^ sw)]        = __float2bfloat16(d0 * rstd * lw[lane] + lb[lane]);
        As[row * 128 + ((lane + 64) ^ sw)] = __float2bfloat16(d1 * rstd * lw[lane + 64] + lb[lane + 64]);
    }
    __syncthreads();
    int r  = lane & 15;
    int kh = lane >> 4;
    f32x4 acc[4][2] = {};
    for (int k0 = 0; k0 < DM; k0 += 32) {
        short8v af[4], bf[2];
#pragma unroll
        for (int i = 0; i < 4; ++i) {
            int row = i * 16 + r;
            int cbk = (k0 >> 3) + kh;
            af[i] = *(const short8v*)&As[row * 128 + ((cbk ^ (row & 7)) << 3)];
        }
#pragma unroll
        for (int j = 0; j < 2; ++j)
            bf[j] = *(const short8v*)&W[(size_t)(nBase + wave * 32 + j * 16 + r) * DM + k0 + kh * 8];
#pragma unroll
        for (int i = 0; i < 4; ++i)
#pragma unroll
            for (int j = 0; j < 2; ++j)
                acc[i][j] = __builtin_amdgcn_mfma_f32_16x16x32_bf16(af[i], bf[j], acc[i][j], 0, 0, 0);
    }
#pragma unroll
    for (int i = 0; i < 4; ++i)
#pragma unroll
        for (int j = 0; j < 2; ++j)
#pragma unroll
            for (int rg = 0; rg < 4; ++rg) {
                size_t off = (size_t)(mBase + i * 16 + kh * 4 + rg) * (2 * DI)
                           + nBase + wave * 32 + j * 16 + r;
                xz[off] = acc[i][j][rg];
            }
}

__global__ __launch_bounds__(256) void w_conv_wx(const float* __restrict__ xz,
    const float* __restrict__ cw, const float* __restrict__ cbs,
    const float* __restrict__ Wx, const float* __restrict__ Wdt, const float* __restrict__ bdt,
    float* __restrict__ xc, float* __restrict__ BC, float* __restrict__ delta) {
    int lane = threadIdx.x & 63;
    int t = blockIdx.x * 4 + (threadIdx.x >> 6);
    int tl = t & (LL - 1);
    int b = t >> 11;
    float xv[4];
#pragma unroll
    for (int j = 0; j < 4; ++j) {
        int e = lane + 64 * j;
        float4 cw0 = *(const float4*)&cw[e * KC];
        float4 cw1 = *(const float4*)&cw[e * KC + 4];
        float wts[8] = {cw0.x, cw0.y, cw0.z, cw0.w, cw1.x, cw1.y, cw1.z, cw1.w};
        float acc = cbs[e];
#pragma unroll
        for (int k = 0; k < KC; ++k) {
            int pos = tl + k - (KC - 1);
            float v = (pos >= 0) ? xz[((size_t)(b * LL + pos) << 9) + e] : 0.f;
            acc = fmaf(v, wts[k], acc);
        }
        xv[j] = acc / (1.f + __expf(-acc));
        xc[((size_t)t << 8) + e] = xv[j];
    }
    float dt[8];
    float bcv = 0.f;
#pragma unroll
    for (int o = 0; o < 40; ++o) {
        const float* w = &Wx[o * DI];
        float s = xv[0] * w[lane];
        s = fmaf(xv[1], w[lane + 64], s);
        s = fmaf(xv[2], w[lane + 128], s);
        s = fmaf(xv[3], w[lane + 192], s);
#pragma unroll
        for (int off = 32; off; off >>= 1) s += __shfl_xor(s, off);
        if (o < 8) dt[o] = s;
        else if (lane == o - 8) bcv = s;
    }
    if (lane < 32) BC[((size_t)t << 5) + lane] = bcv;
#pragma unroll
    for (int j = 0; j < 4; ++j) {
        int e = lane + 64 * j;
        float s = bdt[e];
#pragma unroll
        for (int r = 0; r < 8; ++r) s = fmaf(dt[r], Wdt[e * 8 + r], s);
        delta[((size_t)t << 8) + e] = fmaxf(s, 0.f) + log1pf(__expf(-fabsf(s)));
    }
}

__global__ __launch_bounds__(256) void w_scan1(const float* __restrict__ delta,
    const float* __restrict__ xc, const float* __restrict__ BC,
    const float* __restrict__ A_log,
    __hip_bfloat16* __restrict__ P, __hip_bfloat16* __restrict__ hend) {
    int blk = blockIdx.x, tid = threadIdx.x;
    int eg = blk & 3;
    int c = (blk >> 2) & (NC - 1);
    int b = blk >> 9;
    int e = eg * 64 + (tid >> 2);
    int ng = tid & 3;
    float4 al = *(const float4*)&A_log[e * DS + 4 * ng];
    float Aen[4] = {-__expf(al.x), -__expf(al.y), -__expf(al.z), -__expf(al.w)};
    float h[4] = {}, Pl[4] = {1.f, 1.f, 1.f, 1.f};
    int base = b * LL + c * CT;
    const float* dp = delta + (size_t)base * DI + e;
    const float* up = xc + (size_t)base * DI + e;
    const float* bp = BC + (size_t)base * 32 + 4 * ng;
    for (int l0 = 0; l0 < CT; l0 += SU) {
        float d[SU], uu[SU];
        float4 bm[SU];
#pragma unroll
        for (int j = 0; j < SU; ++j) {
            d[j]  = dp[(l0 + j) * DI];
            uu[j] = up[(l0 + j) * DI];
            bm[j] = *(const float4*)&bp[(l0 + j) * 32];
        }
#pragma unroll
        for (int j = 0; j < SU; ++j) {
            float du = d[j] * uu[j];
            float a0 = __expf(d[j] * Aen[0]);
            float a1 = __expf(d[j] * Aen[1]);
            float a2 = __expf(d[j] * Aen[2]);
            float a3 = __expf(d[j] * Aen[3]);
            h[0] = fmaf(h[0], a0, du * bm[j].x);
            h[1] = fmaf(h[1], a1, du * bm[j].y);
            h[2] = fmaf(h[2], a2, du * bm[j].z);
            h[3] = fmaf(h[3], a3, du * bm[j].w);
            Pl[0] *= a0; Pl[1] *= a1; Pl[2] *= a2; Pl[3] *= a3;
        }
    }
    size_t oidx = (((size_t)(b * NC + c)) * DI + e) * DS + 4 * ng;
    store_bf16x4(&P[oidx], Pl[0], Pl[1], Pl[2], Pl[3]);
    store_bf16x4(&hend[oidx], h[0], h[1], h[2], h[3]);
}

__global__ void w_carry(const __hip_bfloat16* __restrict__ P,
                        const __hip_bfloat16* __restrict__ hend,
                        __hip_bfloat16* __restrict__ hin) {
    int gtid = blockIdx.x * 256 + threadIdx.x;
    int n = gtid & 15;
    int e = (gtid >> 4) & 255;
    int b = gtid >> 12;
    const size_t cs = (size_t)DI * DS;
    size_t idx0 = (((size_t)(b * NC)) * DI + e) * DS + n;
    float carry = 0.f;
    for (int c0 = 0; c0 < NC; c0 += 8) {
        float p[8], he[8];
#pragma unroll
        for (int j = 0; j < 8; ++j) {
            size_t idx = idx0 + (size_t)(c0 + j) * cs;
            p[j]  = __bfloat162float(P[idx]);
            he[j] = __bfloat162float(hend[idx]);
        }
#pragma unroll
        for (int j = 0; j < 8; ++j) {
            hin[idx0 + (size_t)(c0 + j) * cs] = __float2bfloat16(carry);
            carry = fmaf(p[j], carry, he[j]);
        }
    }
}

__global__ __launch_bounds__(256) void w_scan3(const float* __restrict__ delta,
    const float* __restrict__ xc, const float* __restrict__ BC,
    const float* __restrict__ A_log, const __hip_bfloat16* __restrict__ hin,
    const float* __restrict__ xz,
    const float* __restrict__ Dsk, __hip_bfloat16* __restrict__ y) {
    int blk = blockIdx.x, tid = threadIdx.x;
    int eg = blk & 3;
    int c = (blk >> 2) & (NC - 1);
    int b = blk >> 9;
    int e = eg * 64 + (tid >> 2);
    int ng = tid & 3;
    float4 al = *(const float4*)&A_log[e * DS + 4 * ng];
    float Aen[4] = {-__expf(al.x), -__expf(al.y), -__expf(al.z), -__expf(al.w)};
    float dsk = Dsk[e];
    float4 h4 = load_bf16x4(&hin[(((size_t)(b * NC + c)) * DI + e) * DS + 4 * ng]);
    float h[4] = {h4.x, h4.y, h4.z, h4.w};
    int base = b * LL + c * CT;
    const float* dp = delta + (size_t)base * DI + e;
    const float* up = xc + (size_t)base * DI + e;
    const float* bp = BC + (size_t)base * 32 + 4 * ng;
    const float* zp = xz + ((size_t)base << 9) + DI + e;
    __hip_bfloat16* yp = y + (size_t)base * DI + e;
    for (int l0 = 0; l0 < CT; l0 += SU) {
        float d[SU], uu[SU], zv[SU];
        float4 bm[SU], cm[SU];
#pragma unroll
        for (int j = 0; j < SU; ++j) {
            d[j]  = dp[(l0 + j) * DI];
            uu[j] = up[(l0 + j) * DI];
            bm[j] = *(const float4*)&bp[(l0 + j) * 32];
            cm[j] = *(const float4*)&bp[(l0 + j) * 32 + 16];
            zv[j] = zp[(size_t)(l0 + j) << 9];
        }
#pragma unroll
        for (int j = 0; j < SU; ++j) {
            float du = d[j] * uu[j];
            float a0 = __expf(d[j] * Aen[0]);
            float a1 = __expf(d[j] * Aen[1]);
            float a2 = __expf(d[j] * Aen[2]);
            float a3 = __expf(d[j] * Aen[3]);
            h[0] = fmaf(h[0], a0, du * bm[j].x);
            h[1] = fmaf(h[1], a1, du * bm[j].y);
            h[2] = fmaf(h[2], a2, du * bm[j].z);
            h[3] = fmaf(h[3], a3, du * bm[j].w);
            float yc = h[0] * cm[j].x;
            yc = fmaf(h[1], cm[j].y, yc);
            yc = fmaf(h[2], cm[j].z, yc);
            yc = fmaf(h[3], cm[j].w, yc);
            yc += __shfl_xor(yc, 1);
            yc += __shfl_xor(yc, 2);
            if (ng == 0) {
                float z = zv[j];
                float val = (yc + dsk * uu[j]) * (z / (1.f + __expf(-z)));
                yp[(l0 + j) * DI] = __float2bfloat16(val);
            }
        }
    }
}

__global__ __launch_bounds__(256) void w_gemm2(const __hip_bfloat16* __restrict__ A,
                                               const __hip_bfloat16* __restrict__ W,
                                               float* __restrict__ C) {
    int v = blockIdx.x, wave = threadIdx.x >> 6, lane = threadIdx.x & 63;
    int mBase = v * 16;
    int r  = lane & 15;
    int kh = lane >> 4;
    f32x4 acc[2] = {};
    for (int k0 = 0; k0 < DI; k0 += 32) {
        short8v af = *(const short8v*)&A[(size_t)(mBase + r) * DI + k0 + kh * 8];
        short8v bf[2];
#pragma unroll
        for (int j = 0; j < 2; ++j)
            bf[j] = *(const short8v*)&W[(size_t)(wave * 32 + j * 16 + r) * DI + k0 + kh * 8];
#pragma unroll
        for (int j = 0; j < 2; ++j)
            acc[j] = __builtin_amdgcn_mfma_f32_16x16x32_bf16(af, bf[j], acc[j], 0, 0, 0);
    }
#pragma unroll
    for (int j = 0; j < 2; ++j)
#pragma unroll
        for (int rg = 0; rg < 4; ++rg) {
            size_t off = (size_t)(mBase + kh * 4 + rg) * DM + wave * 32 + j * 16 + r;
            C[off] += acc[j][rg];
        }
}

__global__ void w_out(const float* h, const float* ow, const float* ob, float* out) {
    dev_out(blockIdx.x * 4 + (threadIdx.x >> 6), threadIdx.x & 63, h, ow, ob, out);
}

extern "C" void kernel_launch(void* const* d_in, const int* in_sizes, int n_in,
                              void* d_out, int out_size, void* d_ws, size_t ws_size,
                              hipStream_t stream) {
    (void)in_sizes; (void)n_in; (void)out_size; (void)ws_size;
    const float* x      = (const float*)d_in[0];
    const float* pcw    = (const float*)d_in[1];
    const float* pcb    = (const float*)d_in[2];
    const float* ln_w   = (const float*)d_in[3];
    const float* ln_b   = (const float*)d_in[4];
    const float* W_in   = (const float*)d_in[5];
    const float* conv_w = (const float*)d_in[6];
    const float* conv_b = (const float*)d_in[7];
    const float* W_x    = (const float*)d_in[8];
    const float* W_dt   = (const float*)d_in[9];
    const float* b_dt   = (const float*)d_in[10];
    const float* A_log  = (const float*)d_in[11];
    const float* D_skip = (const float*)d_in[12];
    const float* W_out  = (const float*)d_in[13];
    const float* out_w  = (const float*)d_in[14];
    const float* out_b  = (const float*)d_in[15];

    const size_t SCAN_N = (size_t)BB * NC * DI * DS;
    float* ws    = (float*)d_ws;
    float* h     = ws;                              // BL*DM
    float* xz    = h     + (size_t)BL * DM;         // BL*512 (fallback only)
    float* xc    = xz    + (size_t)BL * 2 * DI;     // BL*256 (fallback only)
    float* BC    = xc    + (size_t)BL * DI;         // BL*32  (fallback only)
    float* delta = BC    + (size_t)BL * 2 * DS;     // BL*256 (fallback only)
    __hip_bfloat16* P     = (__hip_bfloat16*)(delta + (size_t)BL * DI);
    __hip_bfloat16* hend  = P + SCAN_N;
    __hip_bfloat16* hin   = hend + SCAN_N;                      // fallback only
    __hip_bfloat16* hincl = hin + SCAN_N;                       // mega only
    __hip_bfloat16* y_bf  = hincl + SCAN_N;                     // BL*DI (fallback only)
    __hip_bfloat16* wi_bf = y_bf + (size_t)BL * DI;             // NB*512*128
    __hip_bfloat16* wo_bf = wi_bf + (size_t)NB * 2 * DI * DM;   // NB*128*256
    __hip_bfloat16* wx_bf = wo_bf + (size_t)NB * DM * DI;       // NB*40*256
    int* flags = (int*)(wx_bf + (size_t)NB * 40 * DI);          // NCHUNK ints

    int dev = 0;
    (void)hipGetDevice(&dev);
    int coopAttr = 0;
    (void)hipDeviceGetAttribute(&coopAttr, hipDeviceAttributeCooperativeLaunch, dev);
    int numCU = 0;
    (void)hipDeviceGetAttribute(&numCU, hipDeviceAttributeMultiprocessorCount, dev);
    int maxBpCU = 0;
    (void)hipOccupancyMaxActiveBlocksPerMultiprocessor(&maxBpCU, k_mega, 512, 0);
    int grid = maxBpCU * numCU;
    if (grid > NCHUNK) grid = NCHUNK;

    bool launched = false;
    if (coopAttr && grid == NCHUNK) {   // lookback requires ALL chunks resident
        MegaArgs ma = {x, pcw, pcb, ln_w, ln_b, conv_w, conv_b,
                       W_x, W_dt, b_dt, A_log, D_skip, W_in, W_out, out_w, out_b,
                       h, (float*)d_out,
                       P, hend, hincl, wi_bf, wo_bf, wx_bf, flags};
        void* kp[] = {&ma};
        hipError_t e = hipLaunchCooperativeKernel((void*)k_mega, dim3(grid), dim3(512), kp, 0, stream);
        launched = (e == hipSuccess);
        if (!launched) (void)hipGetLastError();
    }

    if (!launched) {
        // -------- fallback: proven multi-launch path --------
        w_preconv<<<(BB * LL * DM) / 256, 256, 0, stream>>>(
            x, pcw, pcb, h, W_in, W_out, W_x, wi_bf, wo_bf, wx_bf);
        for (int blk = 0; blk < NB; ++blk) {
            w_ln_gemm1<<<512, 256, 0, stream>>>(
                h, ln_w + blk * DM, ln_b + blk * DM, wi_bf + (size_t)blk * 2 * DI * DM, xz);
            w_conv_wx<<<BL / 4, 256, 0, stream>>>(
                xz, conv_w + (size_t)blk * DI * KC, conv_b + blk * DI,
                W_x + (size_t)blk * 40 * DI, W_dt + (size_t)blk * DI * DTR,
                b_dt + blk * DI, xc, BC, delta);
            w_scan1<<<BB * NC * 4, 256, 0, stream>>>(
                delta, xc, BC, A_log + (size_t)blk * DI * DS, P, hend);
            w_carry<<<(BB * DI * DS) / 256, 256, 0, stream>>>(P, hend, hin);
            w_scan3<<<BB * NC * 4, 256, 0, stream>>>(
                delta, xc, BC, A_log + (size_t)blk * DI * DS, hin, xz, D_skip + blk * DI, y_bf);
            w_gemm2<<<BL / 16, 256, 0, stream>>>(y_bf, wo_bf + (size_t)blk * DM * DI, h);
        }
        w_out<<<BL / 4, 256, 0, stream>>>(h, out_w, out_b, (float*)d_out);
    }
}